// Round 1
// baseline (1209.948 us; speedup 1.0000x reference)
//
#include <hip/hip_runtime.h>
#include <hip/hip_bf16.h>

// Problem sizes (fixed by reference):
// x: (16, 528, 32, 28, 28) fp32; bbox: (256,5); w1:(128,528); w2:(32,128); w3:(1,32)
// out: 256 fp32
#define BB 16
#define CC 528
#define TT 32
#define HW 784        // 28*28
#define NPIX4 196     // 784/4
#define NOUT4 1655808 // 16*528*196
#define NJ 128
#define NROI 256
#define CHUNK 48      // 528 = 11*48

// ---------------- Kernel A: feat[b,c,pix] = mean_t x[b,c,t,pix] ----------------
__global__ __launch_bounds__(256) void tmean_kernel(const float4* __restrict__ x4,
                                                    float4* __restrict__ feat4) {
    int idx = blockIdx.x * 256 + threadIdx.x;
    if (idx >= NOUT4) return;
    int bc = idx / NPIX4;
    int p4 = idx - bc * NPIX4;
    const float4* xp = x4 + (size_t)bc * (TT * NPIX4) + p4;
    float sx = 0.f, sy = 0.f, sz = 0.f, sw = 0.f;
#pragma unroll 8
    for (int t = 0; t < TT; ++t) {
        float4 v = xp[(size_t)t * NPIX4];
        sx += v.x; sy += v.y; sz += v.z; sw += v.w;
    }
    float4 o;
    o.x = sx * 0.03125f; o.y = sy * 0.03125f; o.z = sz * 0.03125f; o.w = sw * 0.03125f;
    feat4[idx] = o;
}

// ---------------- Kernel T: w1T[c][j] = w1[j][c] (one-shot, tiny) ----------------
__global__ void transpose_w1(const float* __restrict__ w1, float* __restrict__ w1T) {
    int c = blockIdx.x;       // 528
    int j = threadIdx.x;      // 128
    w1T[c * NJ + j] = w1[j * CC + c];
}

// ---------------- Kernel B: g[b,pix,j] = sum_c feat[b,c,pix] * w1[j,c] ----------------
// grid (14, 16): pixel tile of 56 (=2 rows), batch b. block 256: jg=tid&31 (4 j's), pr=tid>>5 (7 px's)
__global__ __launch_bounds__(256) void proj_kernel(const float* __restrict__ feat,
                                                   const float* __restrict__ w1T,
                                                   float* __restrict__ g) {
    __shared__ float fs[CHUNK * 56];
    __shared__ float w1s[CHUNK * NJ];
    int tile = blockIdx.x;    // 0..13
    int b = blockIdx.y;       // 0..15
    int tid = threadIdx.x;
    int jg = tid & 31;        // j = 4*jg .. 4*jg+3
    int pr = tid >> 5;        // px = pr*7 .. pr*7+6 (within tile of 56)
    int p0 = tile * 56;
    float acc[4][7];
#pragma unroll
    for (int a = 0; a < 4; ++a)
#pragma unroll
        for (int i = 0; i < 7; ++i) acc[a][i] = 0.f;

    const float* featb = feat + (size_t)b * CC * HW;

    for (int c0 = 0; c0 < CC; c0 += CHUNK) {
        // stage feat chunk [CHUNK][56] (coalesced 56-float rows)
        for (int t = tid; t < CHUNK * 56; t += 256) {
            int cl = t / 56;
            int pp = t - cl * 56;
            fs[t] = featb[(size_t)(c0 + cl) * HW + p0 + pp];
        }
        // stage w1T chunk [CHUNK][128] (fully coalesced)
        for (int t = tid; t < CHUNK * NJ; t += 256) {
            w1s[t] = w1T[c0 * NJ + t];
        }
        __syncthreads();
#pragma unroll 4
        for (int cl = 0; cl < CHUNK; ++cl) {
            float4 wv = *(const float4*)&w1s[cl * NJ + jg * 4];  // b128, conflict-free
            float fv[7];
#pragma unroll
            for (int i = 0; i < 7; ++i) fv[i] = fs[cl * 56 + pr * 7 + i]; // 2-way broadcast, free
#pragma unroll
            for (int i = 0; i < 7; ++i) {
                acc[0][i] += wv.x * fv[i];
                acc[1][i] += wv.y * fv[i];
                acc[2][i] += wv.z * fv[i];
                acc[3][i] += wv.w * fv[i];
            }
        }
        __syncthreads();
    }
    // write g (float4, coalesced)
#pragma unroll
    for (int i = 0; i < 7; ++i) {
        int p = p0 + pr * 7 + i;
        float4* gp = (float4*)(g + ((size_t)b * HW + p) * NJ + jg * 4);
        float4 o;
        o.x = acc[0][i]; o.y = acc[1][i]; o.z = acc[2][i]; o.w = acc[3][i];
        *gp = o;
    }
}

// ---------------- Kernel C: per-ROI bilinear pooling on g + MLP ----------------
__global__ __launch_bounds__(256) void roi_mlp_kernel(const float* __restrict__ g,
                                                      const float* __restrict__ bbox,
                                                      const float* __restrict__ b1,
                                                      const float* __restrict__ w2,
                                                      const float* __restrict__ b2,
                                                      const float* __restrict__ w3,
                                                      const float* __restrict__ b3,
                                                      float* __restrict__ out) {
    __shared__ float red[2][NJ];
    __shared__ float h1s[NJ];
    __shared__ float h2s[32];
    __shared__ float w2s[32 * 129];  // padded stride to avoid bank conflicts
    int r = blockIdx.x;
    int tid = threadIdx.x;

    // stage w2 (coalesced global read, padded LDS write)
    for (int t = tid; t < 32 * NJ; t += 256) {
        w2s[(t >> 7) * 129 + (t & 127)] = w2[t];
    }

    int b = (int)bbox[5 * r];
    float x1 = bbox[5 * r + 1] * 0.0625f - 0.5f;
    float y1 = bbox[5 * r + 2] * 0.0625f - 0.5f;
    float x2 = bbox[5 * r + 3] * 0.0625f - 0.5f;
    float y2 = bbox[5 * r + 4] * 0.0625f - 0.5f;
    float bw = (x2 - x1) * 0.125f;  // /OUT
    float bh = (y2 - y1) * 0.125f;

    int j = tid & 127;
    int grp = tid >> 7;  // 2 sample groups
    const float* gb = g + (size_t)b * HW * NJ;
    float acc = 0.f;

    for (int s = grp; s < 256; s += 2) {
        int iy = s >> 4, ix = s & 15;
        float yy = y1 + (iy + 0.5f) * 0.5f * bh;   // off=(iy+0.5)/SR
        float xx = x1 + (ix + 0.5f) * 0.5f * bw;
        if (yy > -1.f && yy < 28.f && xx > -1.f && xx < 28.f) {
            float yc = fminf(fmaxf(yy, 0.f), 27.f);
            float xc = fminf(fmaxf(xx, 0.f), 27.f);
            int y0 = (int)floorf(yc);
            int x0 = (int)floorf(xc);
            int y1i = min(y0 + 1, 27);
            int x1i = min(x0 + 1, 27);
            float ly = yc - (float)y0, lx = xc - (float)x0;
            float hy = 1.f - ly, hx = 1.f - lx;
            const float* r0 = gb + (size_t)(y0 * 28) * NJ;
            const float* r1p = gb + (size_t)(y1i * 28) * NJ;
            float v00 = r0[x0 * NJ + j];
            float v01 = r0[x1i * NJ + j];
            float v10 = r1p[x0 * NJ + j];
            float v11 = r1p[x1i * NJ + j];
            acc += hy * hx * v00 + hy * lx * v01 + ly * hx * v10 + ly * lx * v11;
        }
    }
    red[grp][j] = acc;
    __syncthreads();
    if (tid < NJ) {
        float tot = (red[0][tid] + red[1][tid]) * (1.f / 256.f) + b1[tid];
        h1s[tid] = fmaxf(tot, 0.f);
    }
    __syncthreads();
    if (tid < 32) {
        float a2 = b2[tid];
#pragma unroll 8
        for (int jj = 0; jj < NJ; ++jj) a2 += w2s[tid * 129 + jj] * h1s[jj];
        h2s[tid] = a2;
    }
    __syncthreads();
    if (tid == 0) {
        float o = b3[0];
#pragma unroll
        for (int k = 0; k < 32; ++k) o += w3[k] * h2s[k];
        out[r] = o;
    }
}

extern "C" void kernel_launch(void* const* d_in, const int* in_sizes, int n_in,
                              void* d_out, int out_size, void* d_ws, size_t ws_size,
                              hipStream_t stream) {
    (void)in_sizes; (void)n_in; (void)out_size; (void)ws_size;
    const float* x    = (const float*)d_in[0];
    const float* bbox = (const float*)d_in[1];
    const float* w1   = (const float*)d_in[2];
    const float* b1   = (const float*)d_in[3];
    const float* w2   = (const float*)d_in[4];
    const float* b2   = (const float*)d_in[5];
    const float* w3   = (const float*)d_in[6];
    const float* b3   = (const float*)d_in[7];
    float* out = (float*)d_out;

    float* feat = (float*)d_ws;                 // 16*528*784   = 6,623,232 floats
    float* g    = feat + (size_t)BB * CC * HW;  // 16*784*128   = 1,605,632 floats
    float* w1T  = g + (size_t)BB * HW * NJ;     // 528*128      =    67,584 floats
                                                // total ~33.2 MB of d_ws

    tmean_kernel<<<NOUT4 / 256, 256, 0, stream>>>((const float4*)x, (float4*)feat);
    transpose_w1<<<CC, NJ, 0, stream>>>(w1, w1T);
    proj_kernel<<<dim3(14, BB), 256, 0, stream>>>(feat, w1T, g);
    roi_mlp_kernel<<<NROI, 256, 0, stream>>>(g, bbox, b1, w2, b2, w3, b3, out);
}

// Round 2
// 1121.952 us; speedup vs baseline: 1.0784x; 1.0784x over previous
//
#include <hip/hip_runtime.h>
#include <hip/hip_bf16.h>

// Problem sizes (fixed by reference):
// x: (16, 528, 32, 28, 28) fp32; bbox: (256,5); w1:(128,528); w2:(32,128); w3:(1,32)
// out: 256 fp32
#define BB 16
#define CC 528
#define TT 32
#define HW 784        // 28*28
#define NJ 128
#define NROI 256
#define CL 8          // channel chunk; 528 = 66*8
#define NCHUNK 66

// ---------------- Kernel T: w1T[c][j] = w1[j][c] (one-shot, tiny) ----------------
__global__ void transpose_w1(const float* __restrict__ w1, float* __restrict__ w1T) {
    int c = blockIdx.x;       // 528
    int j = threadIdx.x;      // 128
    w1T[c * NJ + j] = w1[j * CC + c];
}

// ---------------- Fused kernel: g[b,p,j] = sum_c w1[j,c] * mean_t x[b,c,t,p] ----------------
// grid (14, 16): px tile of 56 (2 rows), batch b. block 448 = 7 waves.
// Staging role: thread -> (cl = tid/56, px = tid%56); sums 32 t's in regs (software-pipelined).
// Compute role: jg = tid&31 (4 j's), pr = tid>>5 in [0,14) (4 px's) -> acc[4][4], all-b128 LDS reads.
__global__ __launch_bounds__(448) void fused_proj_kernel(const float* __restrict__ x,
                                                         const float* __restrict__ w1T,
                                                         float* __restrict__ g) {
    __shared__ __align__(16) float fs[2][CL * 56];     // 2 x 448
    __shared__ __align__(16) float w1s[2][CL * NJ];    // 2 x 1024
    const int tile = blockIdx.x;   // 0..13
    const int b    = blockIdx.y;   // 0..15
    const int tid  = threadIdx.x;
    const int cl   = tid / 56;     // 0..7
    const int px   = tid - cl * 56;
    const int p0   = tile * 56;
    const int jg   = tid & 31;     // j = 4*jg..4*jg+3
    const int pr   = tid >> 5;     // 0..13 -> px = 4*pr..4*pr+3

    const float* xb = x + ((size_t)b * CC + cl) * (size_t)(TT * HW) + p0 + px;

    float acc[4][4];
#pragma unroll
    for (int a = 0; a < 4; ++a)
#pragma unroll
        for (int i = 0; i < 4; ++i) acc[a][i] = 0.f;

    // ---- prologue: load chunk 0 into registers, store to buf 0 ----
    float tv[TT];
#pragma unroll
    for (int t = 0; t < TT; ++t) tv[t] = xb[t * HW];
    float wa = w1T[tid];
    float wb = w1T[448 + tid];
    float wc = (tid < 128) ? w1T[896 + tid] : 0.f;
    {
        float s = 0.f;
#pragma unroll
        for (int t = 0; t < TT; ++t) s += tv[t];
        fs[0][tid] = s * 0.03125f;
        w1s[0][tid] = wa;
        w1s[0][448 + tid] = wb;
        if (tid < 128) w1s[0][896 + tid] = wc;
    }
    __syncthreads();

    for (int ch = 0; ch < NCHUNK; ++ch) {
        const int nxt = ch + 1;
        // ---- issue next chunk's loads (stay in flight during compute) ----
        if (nxt < NCHUNK) {
            const float* xq = xb + (size_t)nxt * (CL * TT * HW);
#pragma unroll
            for (int t = 0; t < TT; ++t) tv[t] = xq[t * HW];
            const float* wq = w1T + nxt * (CL * NJ);
            wa = wq[tid];
            wb = wq[448 + tid];
            if (tid < 128) wc = wq[896 + tid];
        }
        // ---- compute chunk ch from buf (ch&1) ----
        const float* fsb = fs[ch & 1];
        const float* wsb = w1s[ch & 1];
#pragma unroll
        for (int c = 0; c < CL; ++c) {
            float4 wv = *(const float4*)&wsb[c * NJ + jg * 4];   // b128, 2-way bcast
            float4 fv = *(const float4*)&fsb[c * 56 + pr * 4];   // b128, broadcast
            acc[0][0] += wv.x * fv.x; acc[0][1] += wv.x * fv.y; acc[0][2] += wv.x * fv.z; acc[0][3] += wv.x * fv.w;
            acc[1][0] += wv.y * fv.x; acc[1][1] += wv.y * fv.y; acc[1][2] += wv.y * fv.z; acc[1][3] += wv.y * fv.w;
            acc[2][0] += wv.z * fv.x; acc[2][1] += wv.z * fv.y; acc[2][2] += wv.z * fv.z; acc[2][3] += wv.z * fv.w;
            acc[3][0] += wv.w * fv.x; acc[3][1] += wv.w * fv.y; acc[3][2] += wv.w * fv.z; acc[3][3] += wv.w * fv.w;
        }
        // ---- reduce+store next chunk into the other buffer (waits on vmcnt here) ----
        if (nxt < NCHUNK) {
            float s = 0.f;
#pragma unroll
            for (int t = 0; t < TT; ++t) s += tv[t];
            float* fw = fs[nxt & 1];
            float* ww = w1s[nxt & 1];
            fw[tid] = s * 0.03125f;
            ww[tid] = wa;
            ww[448 + tid] = wb;
            if (tid < 128) ww[896 + tid] = wc;
        }
        __syncthreads();   // one barrier per chunk (ping-pong makes it sufficient)
    }

    // ---- write g: 4 px x float4 of j, coalesced ----
    float* gp = g + ((size_t)(b * HW + p0 + pr * 4)) * NJ + jg * 4;
#pragma unroll
    for (int i = 0; i < 4; ++i) {
        float4 o;
        o.x = acc[0][i]; o.y = acc[1][i]; o.z = acc[2][i]; o.w = acc[3][i];
        *(float4*)(gp + (size_t)i * NJ) = o;
    }
}

// ---------------- Kernel C: per-ROI bilinear pooling on g + MLP ----------------
__global__ __launch_bounds__(256) void roi_mlp_kernel(const float* __restrict__ g,
                                                      const float* __restrict__ bbox,
                                                      const float* __restrict__ b1,
                                                      const float* __restrict__ w2,
                                                      const float* __restrict__ b2,
                                                      const float* __restrict__ w3,
                                                      const float* __restrict__ b3,
                                                      float* __restrict__ out) {
    __shared__ float red[2][NJ];
    __shared__ float h1s[NJ];
    __shared__ float h2s[32];
    __shared__ float w2s[32 * 129];  // padded stride to avoid bank conflicts
    int r = blockIdx.x;
    int tid = threadIdx.x;

    // stage w2 (coalesced global read, padded LDS write)
    for (int t = tid; t < 32 * NJ; t += 256) {
        w2s[(t >> 7) * 129 + (t & 127)] = w2[t];
    }

    int b = (int)bbox[5 * r];
    float x1 = bbox[5 * r + 1] * 0.0625f - 0.5f;
    float y1 = bbox[5 * r + 2] * 0.0625f - 0.5f;
    float x2 = bbox[5 * r + 3] * 0.0625f - 0.5f;
    float y2 = bbox[5 * r + 4] * 0.0625f - 0.5f;
    float bw = (x2 - x1) * 0.125f;  // /OUT
    float bh = (y2 - y1) * 0.125f;

    int j = tid & 127;
    int grp = tid >> 7;  // 2 sample groups
    const float* gb = g + (size_t)b * HW * NJ;
    float acc = 0.f;

    for (int s = grp; s < 256; s += 2) {
        int iy = s >> 4, ix = s & 15;
        float yy = y1 + (iy + 0.5f) * 0.5f * bh;   // off=(iy+0.5)/SR
        float xx = x1 + (ix + 0.5f) * 0.5f * bw;
        if (yy > -1.f && yy < 28.f && xx > -1.f && xx < 28.f) {
            float yc = fminf(fmaxf(yy, 0.f), 27.f);
            float xc = fminf(fmaxf(xx, 0.f), 27.f);
            int y0 = (int)floorf(yc);
            int x0 = (int)floorf(xc);
            int y1i = min(y0 + 1, 27);
            int x1i = min(x0 + 1, 27);
            float ly = yc - (float)y0, lx = xc - (float)x0;
            float hy = 1.f - ly, hx = 1.f - lx;
            const float* r0 = gb + (size_t)(y0 * 28) * NJ;
            const float* r1p = gb + (size_t)(y1i * 28) * NJ;
            float v00 = r0[x0 * NJ + j];
            float v01 = r0[x1i * NJ + j];
            float v10 = r1p[x0 * NJ + j];
            float v11 = r1p[x1i * NJ + j];
            acc += hy * hx * v00 + hy * lx * v01 + ly * hx * v10 + ly * lx * v11;
        }
    }
    red[grp][j] = acc;
    __syncthreads();
    if (tid < NJ) {
        float tot = (red[0][tid] + red[1][tid]) * (1.f / 256.f) + b1[tid];
        h1s[tid] = fmaxf(tot, 0.f);
    }
    __syncthreads();
    if (tid < 32) {
        float a2 = b2[tid];
#pragma unroll 8
        for (int jj = 0; jj < NJ; ++jj) a2 += w2s[tid * 129 + jj] * h1s[jj];
        h2s[tid] = a2;
    }
    __syncthreads();
    if (tid == 0) {
        float o = b3[0];
#pragma unroll
        for (int k = 0; k < 32; ++k) o += w3[k] * h2s[k];
        out[r] = o;
    }
}

extern "C" void kernel_launch(void* const* d_in, const int* in_sizes, int n_in,
                              void* d_out, int out_size, void* d_ws, size_t ws_size,
                              hipStream_t stream) {
    (void)in_sizes; (void)n_in; (void)out_size; (void)ws_size;
    const float* x    = (const float*)d_in[0];
    const float* bbox = (const float*)d_in[1];
    const float* w1   = (const float*)d_in[2];
    const float* b1   = (const float*)d_in[3];
    const float* w2   = (const float*)d_in[4];
    const float* b2   = (const float*)d_in[5];
    const float* w3   = (const float*)d_in[6];
    const float* b3   = (const float*)d_in[7];
    float* out = (float*)d_out;

    float* g   = (float*)d_ws;                 // 16*784*128 = 1,605,632 floats (6.4 MB)
    float* w1T = g + (size_t)BB * HW * NJ;     // 528*128    =    67,584 floats

    transpose_w1<<<CC, NJ, 0, stream>>>(w1, w1T);
    fused_proj_kernel<<<dim3(14, BB), 448, 0, stream>>>(x, w1T, g);
    roi_mlp_kernel<<<NROI, 256, 0, stream>>>(g, bbox, b1, w2, b2, w3, b3, out);
}